// Round 2
// baseline (2955.975 us; speedup 1.0000x reference)
//
#include <hip/hip_runtime.h>
#include <hip/hip_bf16.h>
#include <stdint.h>

typedef short short8 __attribute__((ext_vector_type(8)));
typedef float floatx4 __attribute__((ext_vector_type(4)));

static constexpr int KTOT = 4096;
static constexpr int NTOT = 16384;
static constexpr int MTOT = 8192;
static constexpr int BM = 128, BN = 128, BK = 64;
static constexpr int LDSS = 72;            // ushort stride per LDS row (64 + 8 pad)
static constexpr int NSTEP = KTOT / BK;    // 64

__global__ __launch_bounds__(256) void int4_linear_kernel(
    const float* __restrict__ X,
    const uint32_t* __restrict__ Wp,     // int32-promoted packed bytes (1 byte / word)
    const float* __restrict__ scale,
    const float* __restrict__ bias,
    float* __restrict__ Y)
{
  __shared__ ushort As[BM * LDSS];
  __shared__ ushort Bs[BN * LDSS];

  const int t    = threadIdx.x;
  const int lane = t & 63;
  const int wv   = t >> 6;
  const int wr   = wv >> 1;   // wave row 0..1
  const int wc   = wv & 1;    // wave col 0..1

  const int bm0 = blockIdx.y * BM;
  const int bn0 = blockIdx.x * BN;

  // staging assignment: thread t covers row (t>>1), K-half (t&1)*32 of the tile
  const int srow = t >> 1;
  const int sh   = t & 1;

  const float*    ag = X  + (size_t)(bm0 + srow) * KTOT + sh * 32;
  // one uint32 word per packed byte; row stride = KTOT/2 words; 16 words per K-half
  const uint32_t* bg = Wp + (size_t)(bn0 + srow) * (KTOT / 2) + sh * 16;

  float4 areg[8];
  uint4  breg[4];

  // prologue: load tile 0 into regs
  {
    #pragma unroll
    for (int j = 0; j < 8; ++j)
      areg[j] = *reinterpret_cast<const float4*>(ag + j * 4);
    #pragma unroll
    for (int j = 0; j < 4; ++j)
      breg[j] = *reinterpret_cast<const uint4*>(bg + j * 4);
  }

  floatx4 acc[4][4];
  #pragma unroll
  for (int m = 0; m < 4; ++m)
    #pragma unroll
    for (int n = 0; n < 4; ++n)
      acc[m][n] = (floatx4){0.f, 0.f, 0.f, 0.f};

  ushort* adst = &As[srow * LDSS + sh * 32];
  ushort* bdst = &Bs[srow * LDSS + sh * 32];

  for (int ks = 0; ks < NSTEP; ++ks) {
    // ---- store staged regs -> LDS (convert fp32->bf16, unpack int4->bf16)
    {
      uint32_t ab[16];
      #pragma unroll
      for (int j = 0; j < 8; ++j) {
        uint32_t u0 = __builtin_bit_cast(uint32_t, areg[j].x) + 0x8000u;
        uint32_t u1 = __builtin_bit_cast(uint32_t, areg[j].y) + 0x8000u;
        uint32_t u2 = __builtin_bit_cast(uint32_t, areg[j].z) + 0x8000u;
        uint32_t u3 = __builtin_bit_cast(uint32_t, areg[j].w) + 0x8000u;
        // pack high halves: (high16(u1)<<16) | high16(u0)
        ab[2*j]   = __builtin_amdgcn_perm(u1, u0, 0x07060302u);
        ab[2*j+1] = __builtin_amdgcn_perm(u3, u2, 0x07060302u);
      }
      uint32_t bb[16];
      #pragma unroll
      for (int j = 0; j < 4; ++j) {
        const uint32_t wq[4] = {breg[j].x, breg[j].y, breg[j].z, breg[j].w};
        #pragma unroll
        for (int p = 0; p < 4; ++p) {
          const uint32_t w = wq[p];
          // word holds one packed byte in bits[7:0]: low nibble = value 2q, high = 2q+1
          int v0 = ((int)(w << 28)) >> 28;
          int v1 = ((int)(w << 24)) >> 28;
          uint32_t f0 = __builtin_bit_cast(uint32_t, (float)v0);  // exact for ints
          uint32_t f1 = __builtin_bit_cast(uint32_t, (float)v1);
          bb[j*4 + p] = __builtin_amdgcn_perm(f1, f0, 0x07060302u);
        }
      }
      #pragma unroll
      for (int j = 0; j < 4; ++j) {
        *reinterpret_cast<uint4*>(adst + j * 8) = *reinterpret_cast<const uint4*>(&ab[j*4]);
        *reinterpret_cast<uint4*>(bdst + j * 8) = *reinterpret_cast<const uint4*>(&bb[j*4]);
      }
    }
    __syncthreads();

    // ---- prefetch next tile into regs (overlaps MFMA phase below)
    if (ks + 1 < NSTEP) {
      const float*    ap = ag + (ks + 1) * BK;
      const uint32_t* bp = bg + (ks + 1) * (BK / 2);
      #pragma unroll
      for (int j = 0; j < 8; ++j)
        areg[j] = *reinterpret_cast<const float4*>(ap + j * 4);
      #pragma unroll
      for (int j = 0; j < 4; ++j)
        breg[j] = *reinterpret_cast<const uint4*>(bp + j * 4);
    }

    // ---- MFMA on current LDS tile
    #pragma unroll
    for (int kk = 0; kk < 2; ++kk) {
      const int ko = kk * 32 + (lane >> 4) * 8;
      short8 af[4], bf[4];
      #pragma unroll
      for (int m = 0; m < 4; ++m)
        af[m] = *reinterpret_cast<const short8*>(&As[(wr*64 + m*16 + (lane & 15)) * LDSS + ko]);
      #pragma unroll
      for (int n = 0; n < 4; ++n)
        bf[n] = *reinterpret_cast<const short8*>(&Bs[(wc*64 + n*16 + (lane & 15)) * LDSS + ko]);
      #pragma unroll
      for (int m = 0; m < 4; ++m)
        #pragma unroll
        for (int n = 0; n < 4; ++n)
          acc[m][n] = __builtin_amdgcn_mfma_f32_16x16x32_bf16(af[m], bf[n], acc[m][n], 0, 0, 0);
    }
    __syncthreads();
  }

  // ---- epilogue: y = acc * scale[col] + bias[col]
  const int crow = (lane >> 4) * 4;  // C/D: row = (lane>>4)*4 + reg (m89-verified)
  const int ccol = lane & 15;        //      col = lane & 15
  #pragma unroll
  for (int n = 0; n < 4; ++n) {
    const int col  = bn0 + wc * 64 + n * 16 + ccol;
    const float s  = scale[col];
    const float bz = bias[col];
    #pragma unroll
    for (int m = 0; m < 4; ++m) {
      const int row0 = bm0 + wr * 64 + m * 16 + crow;
      float* yp = Y + (size_t)row0 * NTOT + col;
      #pragma unroll
      for (int r = 0; r < 4; ++r)
        yp[(size_t)r * NTOT] = acc[m][n][r] * s + bz;
    }
  }
}

extern "C" void kernel_launch(void* const* d_in, const int* in_sizes, int n_in,
                              void* d_out, int out_size, void* d_ws, size_t ws_size,
                              hipStream_t stream) {
  (void)in_sizes; (void)n_in; (void)out_size; (void)d_ws; (void)ws_size;
  const float*    X     = (const float*)d_in[0];
  const uint32_t* Wp    = (const uint32_t*)d_in[1];
  const float*    scale = (const float*)d_in[2];
  const float*    bias  = (const float*)d_in[3];
  float*          Y     = (float*)d_out;

  dim3 grid(NTOT / BN, MTOT / BM);  // (128, 64)
  int4_linear_kernel<<<grid, 256, 0, stream>>>(X, Wp, scale, bias, Y);
}

// Round 3
// 1582.577 us; speedup vs baseline: 1.8678x; 1.8678x over previous
//
#include <hip/hip_runtime.h>
#include <hip/hip_bf16.h>
#include <stdint.h>

typedef short short8 __attribute__((ext_vector_type(8)));
typedef float floatx4 __attribute__((ext_vector_type(4)));

static constexpr int KTOT = 4096;
static constexpr int NTOT = 16384;
static constexpr int MTOT = 8192;
static constexpr int BM = 128, BN = 128, BK = 64;
static constexpr int NSTEP = KTOT / BK;    // 64

#define GLOAD_LDS16(g, l)                                              \
  __builtin_amdgcn_global_load_lds(                                    \
      (const __attribute__((address_space(1))) void*)(g),              \
      (__attribute__((address_space(3))) void*)(l), 16, 0, 0)

__device__ __forceinline__ uint32_t pack2_bf16_rne(float lo, float hi) {
  uint32_t a = __builtin_bit_cast(uint32_t, lo);
  uint32_t b = __builtin_bit_cast(uint32_t, hi);
  a += 0x7FFFu + ((a >> 16) & 1u);
  b += 0x7FFFu + ((b >> 16) & 1u);
  return __builtin_amdgcn_perm(b, a, 0x07060302u);  // hi16(b)<<16 | hi16(a)
}

// ---------------- converters ----------------

__global__ __launch_bounds__(256) void cvt_x_kernel(
    const float* __restrict__ X, ushort* __restrict__ Xb) {
  const size_t i = (size_t)blockIdx.x * 256 + threadIdx.x;  // 8 floats/thread
  const float4 a = *reinterpret_cast<const float4*>(X + i * 8);
  const float4 b = *reinterpret_cast<const float4*>(X + i * 8 + 4);
  uint4 o;
  o.x = pack2_bf16_rne(a.x, a.y);
  o.y = pack2_bf16_rne(a.z, a.w);
  o.z = pack2_bf16_rne(b.x, b.y);
  o.w = pack2_bf16_rne(b.z, b.w);
  *reinterpret_cast<uint4*>(Xb + i * 8) = o;
}

__global__ __launch_bounds__(256) void cvt_w_kernel(
    const uint32_t* __restrict__ Wp, ushort* __restrict__ Wb) {
  const size_t i = (size_t)blockIdx.x * 256 + threadIdx.x;  // 4 words -> 8 bf16
  const uint4 w = *reinterpret_cast<const uint4*>(Wp + i * 4);
  const uint32_t wd[4] = {w.x, w.y, w.z, w.w};
  uint4 o;
  uint32_t* op = reinterpret_cast<uint32_t*>(&o);
  #pragma unroll
  for (int p = 0; p < 4; ++p) {
    // each int32 word holds one packed byte: low nibble = value 2q, high = 2q+1
    int v0 = ((int)(wd[p] << 28)) >> 28;
    int v1 = ((int)(wd[p] << 24)) >> 28;
    uint32_t f0 = __builtin_bit_cast(uint32_t, (float)v0);  // exact in bf16
    uint32_t f1 = __builtin_bit_cast(uint32_t, (float)v1);
    op[p] = __builtin_amdgcn_perm(f1, f0, 0x07060302u);
  }
  *reinterpret_cast<uint4*>(Wb + i * 8) = o;
}

// ---------------- main bf16 GEMM (m97 structure) ----------------

__global__ __launch_bounds__(256) void gemm_bf16_kernel(
    const ushort* __restrict__ Xb,   // [MTOT][KTOT] bf16
    const ushort* __restrict__ Wb,   // [NTOT][KTOT] bf16 (B^T layout)
    const float* __restrict__ scale,
    const float* __restrict__ bias,
    float* __restrict__ Y)
{
  __shared__ ushort As[BM * BK];   // linear [128][64]
  __shared__ ushort Bs[BN * BK];

  const int t    = threadIdx.x;
  const int lane = t & 63;
  const int wv   = t >> 6;
  const int wr   = wv >> 1;
  const int wc   = wv & 1;

  // XCD-bijective swizzle: 8192 blocks, 1024 per XCD (8192 % 8 == 0)
  const int wg  = blockIdx.x;
  const int swz = ((wg & 7) << 10) | (wg >> 3);
  const int bx  = swz & 127;   // N tile
  const int by  = swz >> 7;    // M tile
  const int bm0 = by * BM;
  const int bn0 = bx * BN;

  // staging: wave wv covers rows wv*32 + j*8 + (lane>>3), 16B per lane
  const int srow = lane >> 3;
  const int scol = (lane & 7) * 8;
  const ushort* ag = Xb + (size_t)(bm0 + wv * 32 + srow) * KTOT + scol;
  const ushort* bg = Wb + (size_t)(bn0 + wv * 32 + srow) * KTOT + scol;
  ushort* asb = &As[wv * 2048];   // wave-uniform LDS base (+ lane*16B by HW)
  ushort* bsb = &Bs[wv * 2048];

  floatx4 acc[4][4];
  #pragma unroll
  for (int m = 0; m < 4; ++m)
    #pragma unroll
    for (int n = 0; n < 4; ++n)
      acc[m][n] = (floatx4){0.f, 0.f, 0.f, 0.f};

  for (int kt = 0; kt < NSTEP; ++kt) {
    #pragma unroll
    for (int j = 0; j < 4; ++j) {
      GLOAD_LDS16(ag + j * 8 * KTOT, asb + j * 512);
      GLOAD_LDS16(bg + j * 8 * KTOT, bsb + j * 512);
    }
    ag += BK; bg += BK;
    __syncthreads();

    #pragma unroll
    for (int kk = 0; kk < 2; ++kk) {
      const int ko = kk * 32 + (lane >> 4) * 8;
      short8 af[4], bf[4];
      #pragma unroll
      for (int m = 0; m < 4; ++m)
        af[m] = *reinterpret_cast<const short8*>(&As[(wr*64 + m*16 + (lane & 15)) * BK + ko]);
      #pragma unroll
      for (int n = 0; n < 4; ++n)
        bf[n] = *reinterpret_cast<const short8*>(&Bs[(wc*64 + n*16 + (lane & 15)) * BK + ko]);
      #pragma unroll
      for (int m = 0; m < 4; ++m)
        #pragma unroll
        for (int n = 0; n < 4; ++n)
          acc[m][n] = __builtin_amdgcn_mfma_f32_16x16x32_bf16(af[m], bf[n], acc[m][n], 0, 0, 0);
    }
    __syncthreads();
  }

  // epilogue: y = acc * scale[col] + bias[col]
  const int crow = (lane >> 4) * 4;  // C/D: row=(lane>>4)*4+reg, col=lane&15 (m89)
  const int ccol = lane & 15;
  #pragma unroll
  for (int n = 0; n < 4; ++n) {
    const int col  = bn0 + wc * 64 + n * 16 + ccol;
    const float s  = scale[col];
    const float bz = bias[col];
    #pragma unroll
    for (int m = 0; m < 4; ++m) {
      const int row0 = bm0 + wr * 64 + m * 16 + crow;
      float* yp = Y + (size_t)row0 * NTOT + col;
      #pragma unroll
      for (int r = 0; r < 4; ++r)
        yp[(size_t)r * NTOT] = acc[m][n][r] * s + bz;
    }
  }
}

// ---------------- fallback: fused kernel (round-2 passing version) ----------------

static constexpr int LDSS = 72;

__global__ __launch_bounds__(256) void int4_linear_fused_kernel(
    const float* __restrict__ X,
    const uint32_t* __restrict__ Wp,
    const float* __restrict__ scale,
    const float* __restrict__ bias,
    float* __restrict__ Y)
{
  __shared__ ushort As[BM * LDSS];
  __shared__ ushort Bs[BN * LDSS];

  const int t    = threadIdx.x;
  const int lane = t & 63;
  const int wv   = t >> 6;
  const int wr   = wv >> 1;
  const int wc   = wv & 1;
  const int bm0 = blockIdx.y * BM;
  const int bn0 = blockIdx.x * BN;
  const int srow = t >> 1;
  const int sh   = t & 1;

  const float*    ag = X  + (size_t)(bm0 + srow) * KTOT + sh * 32;
  const uint32_t* bg = Wp + (size_t)(bn0 + srow) * (KTOT / 2) + sh * 16;

  float4 areg[8];
  uint4  breg[4];
  #pragma unroll
  for (int j = 0; j < 8; ++j) areg[j] = *reinterpret_cast<const float4*>(ag + j * 4);
  #pragma unroll
  for (int j = 0; j < 4; ++j) breg[j] = *reinterpret_cast<const uint4*>(bg + j * 4);

  floatx4 acc[4][4];
  #pragma unroll
  for (int m = 0; m < 4; ++m)
    #pragma unroll
    for (int n = 0; n < 4; ++n)
      acc[m][n] = (floatx4){0.f, 0.f, 0.f, 0.f};

  ushort* adst = &As[srow * LDSS + sh * 32];
  ushort* bdst = &Bs[srow * LDSS + sh * 32];

  for (int ks = 0; ks < NSTEP; ++ks) {
    {
      uint32_t ab[16];
      #pragma unroll
      for (int j = 0; j < 8; ++j) {
        uint32_t u0 = __builtin_bit_cast(uint32_t, areg[j].x) + 0x8000u;
        uint32_t u1 = __builtin_bit_cast(uint32_t, areg[j].y) + 0x8000u;
        uint32_t u2 = __builtin_bit_cast(uint32_t, areg[j].z) + 0x8000u;
        uint32_t u3 = __builtin_bit_cast(uint32_t, areg[j].w) + 0x8000u;
        ab[2*j]   = __builtin_amdgcn_perm(u1, u0, 0x07060302u);
        ab[2*j+1] = __builtin_amdgcn_perm(u3, u2, 0x07060302u);
      }
      uint32_t bb[16];
      #pragma unroll
      for (int j = 0; j < 4; ++j) {
        const uint32_t wq[4] = {breg[j].x, breg[j].y, breg[j].z, breg[j].w};
        #pragma unroll
        for (int p = 0; p < 4; ++p) {
          const uint32_t w = wq[p];
          int v0 = ((int)(w << 28)) >> 28;
          int v1 = ((int)(w << 24)) >> 28;
          uint32_t f0 = __builtin_bit_cast(uint32_t, (float)v0);
          uint32_t f1 = __builtin_bit_cast(uint32_t, (float)v1);
          bb[j*4 + p] = __builtin_amdgcn_perm(f1, f0, 0x07060302u);
        }
      }
      #pragma unroll
      for (int j = 0; j < 4; ++j) {
        *reinterpret_cast<uint4*>(adst + j * 8) = *reinterpret_cast<const uint4*>(&ab[j*4]);
        *reinterpret_cast<uint4*>(bdst + j * 8) = *reinterpret_cast<const uint4*>(&bb[j*4]);
      }
    }
    __syncthreads();

    if (ks + 1 < NSTEP) {
      const float*    ap = ag + (ks + 1) * BK;
      const uint32_t* bp = bg + (ks + 1) * (BK / 2);
      #pragma unroll
      for (int j = 0; j < 8; ++j) areg[j] = *reinterpret_cast<const float4*>(ap + j * 4);
      #pragma unroll
      for (int j = 0; j < 4; ++j) breg[j] = *reinterpret_cast<const uint4*>(bp + j * 4);
    }

    #pragma unroll
    for (int kk = 0; kk < 2; ++kk) {
      const int ko = kk * 32 + (lane >> 4) * 8;
      short8 af[4], bf[4];
      #pragma unroll
      for (int m = 0; m < 4; ++m)
        af[m] = *reinterpret_cast<const short8*>(&As[(wr*64 + m*16 + (lane & 15)) * LDSS + ko]);
      #pragma unroll
      for (int n = 0; n < 4; ++n)
        bf[n] = *reinterpret_cast<const short8*>(&Bs[(wc*64 + n*16 + (lane & 15)) * LDSS + ko]);
      #pragma unroll
      for (int m = 0; m < 4; ++m)
        #pragma unroll
        for (int n = 0; n < 4; ++n)
          acc[m][n] = __builtin_amdgcn_mfma_f32_16x16x32_bf16(af[m], bf[n], acc[m][n], 0, 0, 0);
    }
    __syncthreads();
  }

  const int crow = (lane >> 4) * 4;
  const int ccol = lane & 15;
  #pragma unroll
  for (int n = 0; n < 4; ++n) {
    const int col  = bn0 + wc * 64 + n * 16 + ccol;
    const float s  = scale[col];
    const float bz = bias[col];
    #pragma unroll
    for (int m = 0; m < 4; ++m) {
      const int row0 = bm0 + wr * 64 + m * 16 + crow;
      float* yp = Y + (size_t)row0 * NTOT + col;
      #pragma unroll
      for (int r = 0; r < 4; ++r)
        yp[(size_t)r * NTOT] = acc[m][n][r] * s + bz;
    }
  }
}

// ---------------- launch ----------------

extern "C" void kernel_launch(void* const* d_in, const int* in_sizes, int n_in,
                              void* d_out, int out_size, void* d_ws, size_t ws_size,
                              hipStream_t stream) {
  (void)in_sizes; (void)n_in; (void)out_size;
  const float*    X     = (const float*)d_in[0];
  const uint32_t* Wp    = (const uint32_t*)d_in[1];
  const float*    scale = (const float*)d_in[2];
  const float*    bias  = (const float*)d_in[3];
  float*          Y     = (float*)d_out;

  const size_t xb_bytes = (size_t)MTOT * KTOT * 2;          // 67 MB
  const size_t wb_bytes = (size_t)NTOT * KTOT * 2;          // 134 MB
  if (ws_size >= xb_bytes + wb_bytes) {
    ushort* Xb = (ushort*)d_ws;
    ushort* Wb = (ushort*)((char*)d_ws + xb_bytes);
    // X: 33.5M elems / 8 per thread / 256 = 16384 blocks
    cvt_x_kernel<<<(MTOT * KTOT) / (8 * 256), 256, 0, stream>>>(X, Xb);
    // W: 33.5M words / 4 per thread / 256 = 32768 blocks
    cvt_w_kernel<<<(NTOT * KTOT / 2) / (4 * 256), 256, 0, stream>>>(Wp, Wb);
    gemm_bf16_kernel<<<(MTOT / BM) * (NTOT / BN), 256, 0, stream>>>(Xb, Wb, scale, bias, Y);
  } else {
    dim3 grid(NTOT / BN, MTOT / BM);
    int4_linear_fused_kernel<<<grid, 256, 0, stream>>>(X, Wp, scale, bias, Y);
  }
}

// Round 4
// 1284.848 us; speedup vs baseline: 2.3006x; 1.2317x over previous
//
#include <hip/hip_runtime.h>
#include <hip/hip_bf16.h>
#include <stdint.h>

typedef short short8 __attribute__((ext_vector_type(8)));
typedef float floatx4 __attribute__((ext_vector_type(4)));

static constexpr int KTOT = 4096;
static constexpr int NTOT = 16384;
static constexpr int MTOT = 8192;

#define GLOAD_LDS16(g, l)                                              \
  __builtin_amdgcn_global_load_lds(                                    \
      (const __attribute__((address_space(1))) void*)(g),              \
      (__attribute__((address_space(3))) void*)(l), 16, 0, 0)

__device__ __forceinline__ uint32_t pack2_bf16_rne(float lo, float hi) {
  uint32_t a = __builtin_bit_cast(uint32_t, lo);
  uint32_t b = __builtin_bit_cast(uint32_t, hi);
  a += 0x7FFFu + ((a >> 16) & 1u);
  b += 0x7FFFu + ((b >> 16) & 1u);
  return __builtin_amdgcn_perm(b, a, 0x07060302u);  // hi16(b)<<16 | hi16(a)
}

// ---------------- converters ----------------

__global__ __launch_bounds__(256) void cvt_x_kernel(
    const float* __restrict__ X, ushort* __restrict__ Xb) {
  const size_t i = (size_t)blockIdx.x * 256 + threadIdx.x;  // 8 floats/thread
  const float4 a = *reinterpret_cast<const float4*>(X + i * 8);
  const float4 b = *reinterpret_cast<const float4*>(X + i * 8 + 4);
  uint4 o;
  o.x = pack2_bf16_rne(a.x, a.y);
  o.y = pack2_bf16_rne(a.z, a.w);
  o.z = pack2_bf16_rne(b.x, b.y);
  o.w = pack2_bf16_rne(b.z, b.w);
  *reinterpret_cast<uint4*>(Xb + i * 8) = o;
}

__global__ __launch_bounds__(256) void cvt_w_kernel(
    const uint32_t* __restrict__ Wp, ushort* __restrict__ Wb) {
  const size_t i = (size_t)blockIdx.x * 256 + threadIdx.x;  // 4 words -> 8 bf16
  const uint4 w = *reinterpret_cast<const uint4*>(Wp + i * 4);
  const uint32_t wd[4] = {w.x, w.y, w.z, w.w};
  uint4 o;
  uint32_t* op = reinterpret_cast<uint32_t*>(&o);
  #pragma unroll
  for (int p = 0; p < 4; ++p) {
    // each int32 word holds one packed byte: low nibble = value 2q, high = 2q+1
    int v0 = ((int)(wd[p] << 28)) >> 28;
    int v1 = ((int)(wd[p] << 24)) >> 28;
    uint32_t f0 = __builtin_bit_cast(uint32_t, (float)v0);  // exact in bf16
    uint32_t f1 = __builtin_bit_cast(uint32_t, (float)v1);
    op[p] = __builtin_amdgcn_perm(f1, f0, 0x07060302u);
  }
  *reinterpret_cast<uint4*>(Wb + i * 8) = o;
}

// ---------------- 256x256 8-phase bf16 GEMM (m201-style, BK=32, 4-deep ring) ----------------
// 512 threads = 8 waves (2 M x 4 N). Per-wave output 128x64 -> acc[8][4].
// LDS: A ring 4 x 16KB + B ring 4 x 16KB = 128 KB.
// T2 swizzle byte ^= ((row&3)<<4): applied on global SOURCE (inverse) + ds_read col.
// T3/T4: 2 phases/K-tile, 2 staging loads/phase, boundary vmcnt(8) (never 0 mid-loop).
// T5: setprio around each 16-MFMA cluster.

static constexpr int BM = 256, BN = 256, BK = 32;
static constexpr int NT = KTOT / BK;  // 128 K-tiles

__global__ __launch_bounds__(512, 2) void gemm_bf16_256_kernel(
    const ushort* __restrict__ Xb,   // [MTOT][KTOT] bf16
    const ushort* __restrict__ Wb,   // [NTOT][KTOT] bf16 (B^T layout)
    const float* __restrict__ scale,
    const float* __restrict__ bias,
    float* __restrict__ Y)
{
  __shared__ ushort As[4 * 8192];   // 4 bufs x (256 rows x 32 cols)
  __shared__ ushort Bs[4 * 8192];

  const int t    = threadIdx.x;
  const int lane = t & 63;
  const int wv   = t >> 6;       // 0..7
  const int wr   = wv >> 2;      // 0..1  (M half)
  const int wcn  = wv & 3;       // 0..3  (N quarter)

  // XCD mapping: xcd owns 4 M-tile rows; s>>2 sweeps N so all XCDs share W panels via L3
  const int wg  = blockIdx.x;          // 2048 blocks = 32 bm x 64 bn
  const int xcd = wg & 7;
  const int s   = wg >> 3;             // 0..255
  const int bm0 = (xcd * 4 + (s & 3)) * BM;
  const int bn0 = (s >> 2) * BN;

  // ---- staging addressing (inverse-swizzled global source, linear LDS dest)
  // load j covers rows j*128 + wv*16 + (lane>>2); source col = 8*((lane&3)^((lane>>2)&3))
  const int srow = wv * 16 + (lane >> 2);
  const int scol = 8 * ((lane & 3) ^ ((lane >> 2) & 3));
  const ushort* agA = Xb + (size_t)(bm0 + srow) * KTOT + scol;
  const ushort* agB = Wb + (size_t)(bn0 + srow) * KTOT + scol;
  const size_t rowstep = (size_t)128 * KTOT;   // j=1 offset in source
  ushort* aldsw = As + wv * 512;               // + buf*8192 + j*4096 (lane*16B added by HW)
  ushort* bldsw = Bs + wv * 512;

  // ---- ds_read fragment addressing (swizzled column)
  const int rcol = 8 * ((lane >> 4) ^ (lane & 3));
  const ushort* Abase = As + (wr * 128 + (lane & 15)) * 32 + rcol;  // + buf*8192 + m*512
  const ushort* Bbase = Bs + (wcn * 64 + (lane & 15)) * 32 + rcol;  // + buf*8192 + n*512

  floatx4 acc[8][4];
  #pragma unroll
  for (int m = 0; m < 8; ++m)
    #pragma unroll
    for (int n = 0; n < 4; ++n)
      acc[m][n] = (floatx4){0.f, 0.f, 0.f, 0.f};

  // ---- prologue: stage tiles 0,1,2 (12 loads), wait for tile 0 (keep 8 in flight)
  #pragma unroll
  for (int pt = 0; pt < 3; ++pt) {
    const size_t kof = (size_t)pt * BK;
    GLOAD_LDS16(agA + kof,           aldsw + pt * 8192);
    GLOAD_LDS16(agA + kof + rowstep, aldsw + pt * 8192 + 4096);
    GLOAD_LDS16(agB + kof,           bldsw + pt * 8192);
    GLOAD_LDS16(agB + kof + rowstep, bldsw + pt * 8192 + 4096);
  }
  asm volatile("s_waitcnt vmcnt(8)" ::: "memory");
  __builtin_amdgcn_s_barrier();

  for (int kt = 0; kt < NT; ++kt) {
    const int c  = kt & 3;
    const ushort* Ab = Abase + c * 8192;
    const ushort* Bb = Bbase + c * 8192;
    const int st = kt + 3;
    const bool do_stage = (st < NT);
    const int sb = st & 3;
    const size_t kof = (size_t)st * BK;

    // ================= phase 0: B all, A m0-3; stage next A =================
    short8 bf[4], af[4];
    #pragma unroll
    for (int n = 0; n < 4; ++n)
      bf[n] = *reinterpret_cast<const short8*>(Bb + n * 512);
    #pragma unroll
    for (int m = 0; m < 4; ++m)
      af[m] = *reinterpret_cast<const short8*>(Ab + m * 512);
    if (do_stage) {
      GLOAD_LDS16(agA + kof,           aldsw + sb * 8192);
      GLOAD_LDS16(agA + kof + rowstep, aldsw + sb * 8192 + 4096);
    }
    __builtin_amdgcn_s_barrier();
    asm volatile("s_waitcnt lgkmcnt(0)" ::: "memory");
    __builtin_amdgcn_sched_barrier(0);
    __builtin_amdgcn_s_setprio(1);
    #pragma unroll
    for (int m = 0; m < 4; ++m)
      #pragma unroll
      for (int n = 0; n < 4; ++n)
        acc[m][n] = __builtin_amdgcn_mfma_f32_16x16x32_bf16(af[m], bf[n], acc[m][n], 0, 0, 0);
    __builtin_amdgcn_s_setprio(0);
    __builtin_amdgcn_s_barrier();

    // ================= phase 1: A m4-7 (B kept in regs); stage next B ========
    #pragma unroll
    for (int m = 0; m < 4; ++m)
      af[m] = *reinterpret_cast<const short8*>(Ab + (m + 4) * 512);
    if (do_stage) {
      GLOAD_LDS16(agB + kof,           bldsw + sb * 8192);
      GLOAD_LDS16(agB + kof + rowstep, bldsw + sb * 8192 + 4096);
    }
    __builtin_amdgcn_s_barrier();
    asm volatile("s_waitcnt lgkmcnt(0)" ::: "memory");
    __builtin_amdgcn_sched_barrier(0);
    __builtin_amdgcn_s_setprio(1);
    #pragma unroll
    for (int m = 0; m < 4; ++m)
      #pragma unroll
      for (int n = 0; n < 4; ++n)
        acc[m + 4][n] = __builtin_amdgcn_mfma_f32_16x16x32_bf16(af[m], bf[n], acc[m + 4][n], 0, 0, 0);
    __builtin_amdgcn_s_setprio(0);

    // ---- K-tile boundary: counted vmcnt (tile kt+1 guaranteed landed), never 0 mid-loop
    if (kt + 1 < NT) {
      if (kt + 4 <= NT)      { asm volatile("s_waitcnt vmcnt(8)" ::: "memory"); }
      else if (kt + 3 <= NT) { asm volatile("s_waitcnt vmcnt(4)" ::: "memory"); }
      else                   { asm volatile("s_waitcnt vmcnt(0)" ::: "memory"); }
      __builtin_amdgcn_s_barrier();
    }
  }

  // ---- epilogue: y = acc * scale[col] + bias[col]
  const int crow = (lane >> 4) * 4;  // C/D: row=(lane>>4)*4+reg, col=lane&15 (m89)
  const int ccol = lane & 15;
  #pragma unroll
  for (int n = 0; n < 4; ++n) {
    const int col  = bn0 + wcn * 64 + n * 16 + ccol;
    const float sc = scale[col];
    const float bz = bias[col];
    #pragma unroll
    for (int m = 0; m < 8; ++m) {
      const int row0 = bm0 + wr * 128 + m * 16 + crow;
      float* yp = Y + (size_t)row0 * NTOT + col;
      #pragma unroll
      for (int r = 0; r < 4; ++r)
        yp[(size_t)r * NTOT] = acc[m][n][r] * sc + bz;
    }
  }
}

// ---------------- fallback: fused kernel (round-2 passing version) ----------------

static constexpr int FBM = 128, FBN = 128, FBK = 64;
static constexpr int LDSS = 72;
static constexpr int FNSTEP = KTOT / FBK;

__global__ __launch_bounds__(256) void int4_linear_fused_kernel(
    const float* __restrict__ X,
    const uint32_t* __restrict__ Wp,
    const float* __restrict__ scale,
    const float* __restrict__ bias,
    float* __restrict__ Y)
{
  __shared__ ushort As[FBM * LDSS];
  __shared__ ushort Bs[FBN * LDSS];

  const int t    = threadIdx.x;
  const int lane = t & 63;
  const int wv   = t >> 6;
  const int wr   = wv >> 1;
  const int wc   = wv & 1;
  const int bm0 = blockIdx.y * FBM;
  const int bn0 = blockIdx.x * FBN;
  const int srow = t >> 1;
  const int sh   = t & 1;

  const float*    ag = X  + (size_t)(bm0 + srow) * KTOT + sh * 32;
  const uint32_t* bg = Wp + (size_t)(bn0 + srow) * (KTOT / 2) + sh * 16;

  float4 areg[8];
  uint4  breg[4];
  #pragma unroll
  for (int j = 0; j < 8; ++j) areg[j] = *reinterpret_cast<const float4*>(ag + j * 4);
  #pragma unroll
  for (int j = 0; j < 4; ++j) breg[j] = *reinterpret_cast<const uint4*>(bg + j * 4);

  floatx4 acc[4][4];
  #pragma unroll
  for (int m = 0; m < 4; ++m)
    #pragma unroll
    for (int n = 0; n < 4; ++n)
      acc[m][n] = (floatx4){0.f, 0.f, 0.f, 0.f};

  ushort* adst = &As[srow * LDSS + sh * 32];
  ushort* bdst = &Bs[srow * LDSS + sh * 32];

  for (int ks = 0; ks < FNSTEP; ++ks) {
    {
      uint32_t ab[16];
      #pragma unroll
      for (int j = 0; j < 8; ++j) {
        uint32_t u0 = __builtin_bit_cast(uint32_t, areg[j].x) + 0x8000u;
        uint32_t u1 = __builtin_bit_cast(uint32_t, areg[j].y) + 0x8000u;
        uint32_t u2 = __builtin_bit_cast(uint32_t, areg[j].z) + 0x8000u;
        uint32_t u3 = __builtin_bit_cast(uint32_t, areg[j].w) + 0x8000u;
        ab[2*j]   = __builtin_amdgcn_perm(u1, u0, 0x07060302u);
        ab[2*j+1] = __builtin_amdgcn_perm(u3, u2, 0x07060302u);
      }
      uint32_t bb[16];
      #pragma unroll
      for (int j = 0; j < 4; ++j) {
        const uint32_t wq[4] = {breg[j].x, breg[j].y, breg[j].z, breg[j].w};
        #pragma unroll
        for (int p = 0; p < 4; ++p) {
          const uint32_t w = wq[p];
          int v0 = ((int)(w << 28)) >> 28;
          int v1 = ((int)(w << 24)) >> 28;
          uint32_t f0 = __builtin_bit_cast(uint32_t, (float)v0);
          uint32_t f1 = __builtin_bit_cast(uint32_t, (float)v1);
          bb[j*4 + p] = __builtin_amdgcn_perm(f1, f0, 0x07060302u);
        }
      }
      #pragma unroll
      for (int j = 0; j < 4; ++j) {
        *reinterpret_cast<uint4*>(adst + j * 8) = *reinterpret_cast<const uint4*>(&ab[j*4]);
        *reinterpret_cast<uint4*>(bdst + j * 8) = *reinterpret_cast<const uint4*>(&bb[j*4]);
      }
    }
    __syncthreads();

    if (ks + 1 < FNSTEP) {
      const float*    ap = ag + (ks + 1) * FBK;
      const uint32_t* bp = bg + (ks + 1) * (FBK / 2);
      #pragma unroll
      for (int j = 0; j < 8; ++j) areg[j] = *reinterpret_cast<const float4*>(ap + j * 4);
      #pragma unroll
      for (int j = 0; j < 4; ++j) breg[j] = *reinterpret_cast<const uint4*>(bp + j * 4);
    }

    #pragma unroll
    for (int kk = 0; kk < 2; ++kk) {
      const int ko = kk * 32 + (lane >> 4) * 8;
      short8 af[4], bf[4];
      #pragma unroll
      for (int m = 0; m < 4; ++m)
        af[m] = *reinterpret_cast<const short8*>(&As[(wr*64 + m*16 + (lane & 15)) * LDSS + ko]);
      #pragma unroll
      for (int n = 0; n < 4; ++n)
        bf[n] = *reinterpret_cast<const short8*>(&Bs[(wc*64 + n*16 + (lane & 15)) * LDSS + ko]);
      #pragma unroll
      for (int m = 0; m < 4; ++m)
        #pragma unroll
        for (int n = 0; n < 4; ++n)
          acc[m][n] = __builtin_amdgcn_mfma_f32_16x16x32_bf16(af[m], bf[n], acc[m][n], 0, 0, 0);
    }
    __syncthreads();
  }

  const int crow = (lane >> 4) * 4;
  const int ccol = lane & 15;
  #pragma unroll
  for (int n = 0; n < 4; ++n) {
    const int col  = bn0 + wc * 64 + n * 16 + ccol;
    const float s  = scale[col];
    const float bz = bias[col];
    #pragma unroll
    for (int m = 0; m < 4; ++m) {
      const int row0 = bm0 + wr * 64 + m * 16 + crow;
      float* yp = Y + (size_t)row0 * NTOT + col;
      #pragma unroll
      for (int r = 0; r < 4; ++r)
        yp[(size_t)r * NTOT] = acc[m][n][r] * s + bz;
    }
  }
}

// ---------------- launch ----------------

extern "C" void kernel_launch(void* const* d_in, const int* in_sizes, int n_in,
                              void* d_out, int out_size, void* d_ws, size_t ws_size,
                              hipStream_t stream) {
  (void)in_sizes; (void)n_in; (void)out_size;
  const float*    X     = (const float*)d_in[0];
  const uint32_t* Wp    = (const uint32_t*)d_in[1];
  const float*    scale = (const float*)d_in[2];
  const float*    bias  = (const float*)d_in[3];
  float*          Y     = (float*)d_out;

  const size_t xb_bytes = (size_t)MTOT * KTOT * 2;          // 67 MB
  const size_t wb_bytes = (size_t)NTOT * KTOT * 2;          // 134 MB
  if (ws_size >= xb_bytes + wb_bytes) {
    ushort* Xb = (ushort*)d_ws;
    ushort* Wb = (ushort*)((char*)d_ws + xb_bytes);
    cvt_x_kernel<<<(MTOT * KTOT) / (8 * 256), 256, 0, stream>>>(X, Xb);
    cvt_w_kernel<<<(NTOT * KTOT / 2) / (4 * 256), 256, 0, stream>>>(Wp, Wb);
    gemm_bf16_256_kernel<<<(MTOT / BM) * (NTOT / BN), 512, 0, stream>>>(Xb, Wb, scale, bias, Y);
  } else {
    dim3 grid(NTOT / FBN, MTOT / FBM);
    int4_linear_fused_kernel<<<grid, 256, 0, stream>>>(X, Wp, scale, bias, Y);
  }
}

// Round 5
// 1282.111 us; speedup vs baseline: 2.3056x; 1.0021x over previous
//
#include <hip/hip_runtime.h>
#include <hip/hip_bf16.h>
#include <stdint.h>

typedef short short8 __attribute__((ext_vector_type(8)));
typedef float floatx4 __attribute__((ext_vector_type(4)));

static constexpr int KTOT = 4096;
static constexpr int NTOT = 16384;
static constexpr int MTOT = 8192;

#define GLOAD_LDS16(g, l)                                              \
  __builtin_amdgcn_global_load_lds(                                    \
      (const __attribute__((address_space(1))) void*)(g),              \
      (__attribute__((address_space(3))) void*)(l), 16, 0, 0)

__device__ __forceinline__ uint32_t pack2_bf16_rne(float lo, float hi) {
  uint32_t a = __builtin_bit_cast(uint32_t, lo);
  uint32_t b = __builtin_bit_cast(uint32_t, hi);
  a += 0x7FFFu + ((a >> 16) & 1u);
  b += 0x7FFFu + ((b >> 16) & 1u);
  return __builtin_amdgcn_perm(b, a, 0x07060302u);  // hi16(b)<<16 | hi16(a)
}

// ---------------- converters ----------------

__global__ __launch_bounds__(256) void cvt_x_kernel(
    const float* __restrict__ X, ushort* __restrict__ Xb) {
  const size_t i = (size_t)blockIdx.x * 256 + threadIdx.x;  // 8 floats/thread
  const float4 a = *reinterpret_cast<const float4*>(X + i * 8);
  const float4 b = *reinterpret_cast<const float4*>(X + i * 8 + 4);
  uint4 o;
  o.x = pack2_bf16_rne(a.x, a.y);
  o.y = pack2_bf16_rne(a.z, a.w);
  o.z = pack2_bf16_rne(b.x, b.y);
  o.w = pack2_bf16_rne(b.z, b.w);
  *reinterpret_cast<uint4*>(Xb + i * 8) = o;
}

__global__ __launch_bounds__(256) void cvt_w_kernel(
    const uint32_t* __restrict__ Wp, ushort* __restrict__ Wb) {
  const size_t i = (size_t)blockIdx.x * 256 + threadIdx.x;  // 4 words -> 8 bf16
  const uint4 w = *reinterpret_cast<const uint4*>(Wp + i * 4);
  const uint32_t wd[4] = {w.x, w.y, w.z, w.w};
  uint4 o;
  uint32_t* op = reinterpret_cast<uint32_t*>(&o);
  #pragma unroll
  for (int p = 0; p < 4; ++p) {
    // each int32 word holds one packed byte: low nibble = value 2q, high = 2q+1
    int v0 = ((int)(wd[p] << 28)) >> 28;
    int v1 = ((int)(wd[p] << 24)) >> 28;
    uint32_t f0 = __builtin_bit_cast(uint32_t, (float)v0);  // exact in bf16
    uint32_t f1 = __builtin_bit_cast(uint32_t, (float)v1);
    op[p] = __builtin_amdgcn_perm(f1, f0, 0x07060302u);
  }
  *reinterpret_cast<uint4*>(Wb + i * 8) = o;
}

// ---------------- 256x256 8-phase bf16 GEMM (m201-style, BK=32, 4-deep ring) ----------------
// 512 threads = 8 waves (2 M x 4 N). Per-wave output 128x64 -> acc[8][4].
// LDS: A ring 4 x 16KB + B ring 4 x 16KB = 128 KB.
// T2 swizzle (full-strength): phys chunk c = p ^ (row&3) ^ ((row>>2)&3).
//   A 16-lane b128 phase then covers all 8 bank-quads exactly 2x = conflict-free floor.
//   Applied on global SOURCE (per-lane addr, linear global_load_lds dest) + ds_read col.
// T3/T4: 2 phases/K-tile, 2 staging loads/phase, boundary vmcnt(8) (never 0 mid-loop).
// T5: setprio around each 16-MFMA cluster.

static constexpr int BM = 256, BN = 256, BK = 32;
static constexpr int NT = KTOT / BK;  // 128 K-tiles

__global__ __launch_bounds__(512, 2) void gemm_bf16_256_kernel(
    const ushort* __restrict__ Xb,   // [MTOT][KTOT] bf16
    const ushort* __restrict__ Wb,   // [NTOT][KTOT] bf16 (B^T layout)
    const float* __restrict__ scale,
    const float* __restrict__ bias,
    float* __restrict__ Y)
{
  __shared__ ushort As[4 * 8192];   // 4 bufs x (256 rows x 32 cols)
  __shared__ ushort Bs[4 * 8192];

  const int t    = threadIdx.x;
  const int lane = t & 63;
  const int wv   = t >> 6;       // 0..7
  const int wr   = wv >> 2;      // 0..1  (M half)
  const int wcn  = wv & 3;       // 0..3  (N quarter)

  // XCD mapping: xcd owns 4 M-tile rows; s>>2 sweeps N so all XCDs share W panels via L3
  const int wg  = blockIdx.x;          // 2048 blocks = 32 bm x 64 bn
  const int xcd = wg & 7;
  const int s   = wg >> 3;             // 0..255
  const int bm0 = (xcd * 4 + (s & 3)) * BM;
  const int bn0 = (s >> 2) * BN;

  // ---- staging addressing (inverse-swizzled global source, linear LDS dest)
  // thread l, load j covers LDS row = j*128 + wv*16 + (l>>2), phys chunk l&3.
  // content must be logical chunk (l&3) ^ f(row); f(row)=(row&3)^((row>>2)&3)
  //   row&3 = (l>>2)&3, (row>>2)&3 = l>>4  (wv*16, j*128 vanish mod 4 at both shifts)
  const int srow = wv * 16 + (lane >> 2);
  const int scol = 8 * ((lane & 3) ^ ((lane >> 2) & 3) ^ (lane >> 4));
  const ushort* agA = Xb + (size_t)(bm0 + srow) * KTOT + scol;
  const ushort* agB = Wb + (size_t)(bn0 + srow) * KTOT + scol;
  const size_t rowstep = (size_t)128 * KTOT;   // j=1 offset in source
  ushort* aldsw = As + wv * 512;               // + buf*8192 + j*4096 (lane*16B added by HW)
  ushort* bldsw = Bs + wv * 512;

  // ---- ds_read fragment addressing (swizzled column)
  // logical chunk p = lane>>4 of row r; r&3 = lane&3, (r>>2)&3 = (lane>>2)&3
  // for every (wr,m) and (wcn,n) since all tile-base terms are 0 mod 4 at both shifts
  const int rcol = 8 * ((lane >> 4) ^ (lane & 3) ^ ((lane >> 2) & 3));
  const ushort* Abase = As + (wr * 128 + (lane & 15)) * 32 + rcol;  // + buf*8192 + m*512
  const ushort* Bbase = Bs + (wcn * 64 + (lane & 15)) * 32 + rcol;  // + buf*8192 + n*512

  floatx4 acc[8][4];
  #pragma unroll
  for (int m = 0; m < 8; ++m)
    #pragma unroll
    for (int n = 0; n < 4; ++n)
      acc[m][n] = (floatx4){0.f, 0.f, 0.f, 0.f};

  // ---- prologue: stage tiles 0,1,2 (12 loads), wait for tile 0 (keep 8 in flight)
  #pragma unroll
  for (int pt = 0; pt < 3; ++pt) {
    const size_t kof = (size_t)pt * BK;
    GLOAD_LDS16(agA + kof,           aldsw + pt * 8192);
    GLOAD_LDS16(agA + kof + rowstep, aldsw + pt * 8192 + 4096);
    GLOAD_LDS16(agB + kof,           bldsw + pt * 8192);
    GLOAD_LDS16(agB + kof + rowstep, bldsw + pt * 8192 + 4096);
  }
  asm volatile("s_waitcnt vmcnt(8)" ::: "memory");
  __builtin_amdgcn_s_barrier();

  for (int kt = 0; kt < NT; ++kt) {
    const int c  = kt & 3;
    const ushort* Ab = Abase + c * 8192;
    const ushort* Bb = Bbase + c * 8192;
    const int st = kt + 3;
    const bool do_stage = (st < NT);
    const int sb = st & 3;
    const size_t kof = (size_t)st * BK;

    // ================= phase 0: B all, A m0-3; stage next A =================
    short8 bf[4], af[4];
    #pragma unroll
    for (int n = 0; n < 4; ++n)
      bf[n] = *reinterpret_cast<const short8*>(Bb + n * 512);
    #pragma unroll
    for (int m = 0; m < 4; ++m)
      af[m] = *reinterpret_cast<const short8*>(Ab + m * 512);
    if (do_stage) {
      GLOAD_LDS16(agA + kof,           aldsw + sb * 8192);
      GLOAD_LDS16(agA + kof + rowstep, aldsw + sb * 8192 + 4096);
    }
    __builtin_amdgcn_s_barrier();
    asm volatile("s_waitcnt lgkmcnt(0)" ::: "memory");
    __builtin_amdgcn_sched_barrier(0);
    __builtin_amdgcn_s_setprio(1);
    #pragma unroll
    for (int m = 0; m < 4; ++m)
      #pragma unroll
      for (int n = 0; n < 4; ++n)
        acc[m][n] = __builtin_amdgcn_mfma_f32_16x16x32_bf16(af[m], bf[n], acc[m][n], 0, 0, 0);
    __builtin_amdgcn_s_setprio(0);
    __builtin_amdgcn_s_barrier();

    // ================= phase 1: A m4-7 (B kept in regs); stage next B ========
    #pragma unroll
    for (int m = 0; m < 4; ++m)
      af[m] = *reinterpret_cast<const short8*>(Ab + (m + 4) * 512);
    if (do_stage) {
      GLOAD_LDS16(agB + kof,           bldsw + sb * 8192);
      GLOAD_LDS16(agB + kof + rowstep, bldsw + sb * 8192 + 4096);
    }
    __builtin_amdgcn_s_barrier();
    asm volatile("s_waitcnt lgkmcnt(0)" ::: "memory");
    __builtin_amdgcn_sched_barrier(0);
    __builtin_amdgcn_s_setprio(1);
    #pragma unroll
    for (int m = 0; m < 4; ++m)
      #pragma unroll
      for (int n = 0; n < 4; ++n)
        acc[m + 4][n] = __builtin_amdgcn_mfma_f32_16x16x32_bf16(af[m], bf[n], acc[m + 4][n], 0, 0, 0);
    __builtin_amdgcn_s_setprio(0);

    // ---- K-tile boundary: counted vmcnt (tile kt+1 guaranteed landed), never 0 mid-loop
    if (kt + 1 < NT) {
      if (kt + 4 <= NT)      { asm volatile("s_waitcnt vmcnt(8)" ::: "memory"); }
      else if (kt + 3 <= NT) { asm volatile("s_waitcnt vmcnt(4)" ::: "memory"); }
      else                   { asm volatile("s_waitcnt vmcnt(0)" ::: "memory"); }
      __builtin_amdgcn_s_barrier();
    }
  }

  // ---- epilogue: y = acc * scale[col] + bias[col]
  const int crow = (lane >> 4) * 4;  // C/D: row=(lane>>4)*4+reg, col=lane&15 (m89)
  const int ccol = lane & 15;
  #pragma unroll
  for (int n = 0; n < 4; ++n) {
    const int col  = bn0 + wcn * 64 + n * 16 + ccol;
    const float sc = scale[col];
    const float bz = bias[col];
    #pragma unroll
    for (int m = 0; m < 8; ++m) {
      const int row0 = bm0 + wr * 128 + m * 16 + crow;
      float* yp = Y + (size_t)row0 * NTOT + col;
      #pragma unroll
      for (int r = 0; r < 4; ++r)
        yp[(size_t)r * NTOT] = acc[m][n][r] * sc + bz;
    }
  }
}

// ---------------- fallback: fused kernel (round-2 passing version) ----------------

static constexpr int FBM = 128, FBN = 128, FBK = 64;
static constexpr int LDSS = 72;
static constexpr int FNSTEP = KTOT / FBK;

__global__ __launch_bounds__(256) void int4_linear_fused_kernel(
    const float* __restrict__ X,
    const uint32_t* __restrict__ Wp,
    const float* __restrict__ scale,
    const float* __restrict__ bias,
    float* __restrict__ Y)
{
  __shared__ ushort As[FBM * LDSS];
  __shared__ ushort Bs[FBN * LDSS];

  const int t    = threadIdx.x;
  const int lane = t & 63;
  const int wv   = t >> 6;
  const int wr   = wv >> 1;
  const int wc   = wv & 1;
  const int bm0 = blockIdx.y * FBM;
  const int bn0 = blockIdx.x * FBN;
  const int srow = t >> 1;
  const int sh   = t & 1;

  const float*    ag = X  + (size_t)(bm0 + srow) * KTOT + sh * 32;
  const uint32_t* bg = Wp + (size_t)(bn0 + srow) * (KTOT / 2) + sh * 16;

  float4 areg[8];
  uint4  breg[4];
  #pragma unroll
  for (int j = 0; j < 8; ++j) areg[j] = *reinterpret_cast<const float4*>(ag + j * 4);
  #pragma unroll
  for (int j = 0; j < 4; ++j) breg[j] = *reinterpret_cast<const uint4*>(bg + j * 4);

  floatx4 acc[4][4];
  #pragma unroll
  for (int m = 0; m < 4; ++m)
    #pragma unroll
    for (int n = 0; n < 4; ++n)
      acc[m][n] = (floatx4){0.f, 0.f, 0.f, 0.f};

  ushort* adst = &As[srow * LDSS + sh * 32];
  ushort* bdst = &Bs[srow * LDSS + sh * 32];

  for (int ks = 0; ks < FNSTEP; ++ks) {
    {
      uint32_t ab[16];
      #pragma unroll
      for (int j = 0; j < 8; ++j) {
        uint32_t u0 = __builtin_bit_cast(uint32_t, areg[j].x) + 0x8000u;
        uint32_t u1 = __builtin_bit_cast(uint32_t, areg[j].y) + 0x8000u;
        uint32_t u2 = __builtin_bit_cast(uint32_t, areg[j].z) + 0x8000u;
        uint32_t u3 = __builtin_bit_cast(uint32_t, areg[j].w) + 0x8000u;
        ab[2*j]   = __builtin_amdgcn_perm(u1, u0, 0x07060302u);
        ab[2*j+1] = __builtin_amdgcn_perm(u3, u2, 0x07060302u);
      }
      uint32_t bb[16];
      #pragma unroll
      for (int j = 0; j < 4; ++j) {
        const uint32_t wq[4] = {breg[j].x, breg[j].y, breg[j].z, breg[j].w};
        #pragma unroll
        for (int p = 0; p < 4; ++p) {
          const uint32_t w = wq[p];
          int v0 = ((int)(w << 28)) >> 28;
          int v1 = ((int)(w << 24)) >> 28;
          uint32_t f0 = __builtin_bit_cast(uint32_t, (float)v0);
          uint32_t f1 = __builtin_bit_cast(uint32_t, (float)v1);
          bb[j*4 + p] = __builtin_amdgcn_perm(f1, f0, 0x07060302u);
        }
      }
      #pragma unroll
      for (int j = 0; j < 4; ++j) {
        *reinterpret_cast<uint4*>(adst + j * 8) = *reinterpret_cast<const uint4*>(&ab[j*4]);
        *reinterpret_cast<uint4*>(bdst + j * 8) = *reinterpret_cast<const uint4*>(&bb[j*4]);
      }
    }
    __syncthreads();

    if (ks + 1 < FNSTEP) {
      const float*    ap = ag + (ks + 1) * FBK;
      const uint32_t* bp = bg + (ks + 1) * (FBK / 2);
      #pragma unroll
      for (int j = 0; j < 8; ++j) areg[j] = *reinterpret_cast<const float4*>(ap + j * 4);
      #pragma unroll
      for (int j = 0; j < 4; ++j) breg[j] = *reinterpret_cast<const uint4*>(bp + j * 4);
    }

    #pragma unroll
    for (int kk = 0; kk < 2; ++kk) {
      const int ko = kk * 32 + (lane >> 4) * 8;
      short8 af[4], bf[4];
      #pragma unroll
      for (int m = 0; m < 4; ++m)
        af[m] = *reinterpret_cast<const short8*>(&As[(wr*64 + m*16 + (lane & 15)) * LDSS + ko]);
      #pragma unroll
      for (int n = 0; n < 4; ++n)
        bf[n] = *reinterpret_cast<const short8*>(&Bs[(wc*64 + n*16 + (lane & 15)) * LDSS + ko]);
      #pragma unroll
      for (int m = 0; m < 4; ++m)
        #pragma unroll
        for (int n = 0; n < 4; ++n)
          acc[m][n] = __builtin_amdgcn_mfma_f32_16x16x32_bf16(af[m], bf[n], acc[m][n], 0, 0, 0);
    }
    __syncthreads();
  }

  const int crow = (lane >> 4) * 4;
  const int ccol = lane & 15;
  #pragma unroll
  for (int n = 0; n < 4; ++n) {
    const int col  = bn0 + wc * 64 + n * 16 + ccol;
    const float s  = scale[col];
    const float bz = bias[col];
    #pragma unroll
    for (int m = 0; m < 4; ++m) {
      const int row0 = bm0 + wr * 64 + m * 16 + crow;
      float* yp = Y + (size_t)row0 * NTOT + col;
      #pragma unroll
      for (int r = 0; r < 4; ++r)
        yp[(size_t)r * NTOT] = acc[m][n][r] * s + bz;
    }
  }
}

// ---------------- launch ----------------

extern "C" void kernel_launch(void* const* d_in, const int* in_sizes, int n_in,
                              void* d_out, int out_size, void* d_ws, size_t ws_size,
                              hipStream_t stream) {
  (void)in_sizes; (void)n_in; (void)out_size;
  const float*    X     = (const float*)d_in[0];
  const uint32_t* Wp    = (const uint32_t*)d_in[1];
  const float*    scale = (const float*)d_in[2];
  const float*    bias  = (const float*)d_in[3];
  float*          Y     = (float*)d_out;

  const size_t xb_bytes = (size_t)MTOT * KTOT * 2;          // 67 MB
  const size_t wb_bytes = (size_t)NTOT * KTOT * 2;          // 134 MB
  if (ws_size >= xb_bytes + wb_bytes) {
    ushort* Xb = (ushort*)d_ws;
    ushort* Wb = (ushort*)((char*)d_ws + xb_bytes);
    cvt_x_kernel<<<(MTOT * KTOT) / (8 * 256), 256, 0, stream>>>(X, Xb);
    cvt_w_kernel<<<(NTOT * KTOT / 2) / (4 * 256), 256, 0, stream>>>(Wp, Wb);
    gemm_bf16_256_kernel<<<(MTOT / BM) * (NTOT / BN), 512, 0, stream>>>(Xb, Wb, scale, bias, Y);
  } else {
    dim3 grid(NTOT / FBN, MTOT / FBM);
    int4_linear_fused_kernel<<<grid, 256, 0, stream>>>(X, Wp, scale, bias, Y);
  }
}

// Round 6
// 1181.943 us; speedup vs baseline: 2.5009x; 1.0847x over previous
//
#include <hip/hip_runtime.h>
#include <hip/hip_bf16.h>
#include <stdint.h>

typedef short short8 __attribute__((ext_vector_type(8)));
typedef float floatx4 __attribute__((ext_vector_type(4)));

static constexpr int KTOT = 4096;
static constexpr int NTOT = 16384;
static constexpr int MTOT = 8192;

#define GLOAD_LDS16(g, l)                                              \
  __builtin_amdgcn_global_load_lds(                                    \
      (const __attribute__((address_space(1))) void*)(g),              \
      (__attribute__((address_space(3))) void*)(l), 16, 0, 0)

__device__ __forceinline__ uint32_t pack2_bf16_rne(float lo, float hi) {
  uint32_t a = __builtin_bit_cast(uint32_t, lo);
  uint32_t b = __builtin_bit_cast(uint32_t, hi);
  a += 0x7FFFu + ((a >> 16) & 1u);
  b += 0x7FFFu + ((b >> 16) & 1u);
  return __builtin_amdgcn_perm(b, a, 0x07060302u);  // hi16(b)<<16 | hi16(a)
}

// ---------------- converters ----------------

__global__ __launch_bounds__(256) void cvt_x_kernel(
    const float* __restrict__ X, ushort* __restrict__ Xb) {
  const size_t i = (size_t)blockIdx.x * 256 + threadIdx.x;  // 8 floats/thread
  const float4 a = *reinterpret_cast<const float4*>(X + i * 8);
  const float4 b = *reinterpret_cast<const float4*>(X + i * 8 + 4);
  uint4 o;
  o.x = pack2_bf16_rne(a.x, a.y);
  o.y = pack2_bf16_rne(a.z, a.w);
  o.z = pack2_bf16_rne(b.x, b.y);
  o.w = pack2_bf16_rne(b.z, b.w);
  *reinterpret_cast<uint4*>(Xb + i * 8) = o;
}

__global__ __launch_bounds__(256) void cvt_w_kernel(
    const uint32_t* __restrict__ Wp, ushort* __restrict__ Wb) {
  const size_t i = (size_t)blockIdx.x * 256 + threadIdx.x;  // 4 words -> 8 bf16
  const uint4 w = *reinterpret_cast<const uint4*>(Wp + i * 4);
  const uint32_t wd[4] = {w.x, w.y, w.z, w.w};
  uint4 o;
  uint32_t* op = reinterpret_cast<uint32_t*>(&o);
  #pragma unroll
  for (int p = 0; p < 4; ++p) {
    // each int32 word holds one packed byte: low nibble = value 2q, high = 2q+1
    int v0 = ((int)(wd[p] << 28)) >> 28;
    int v1 = ((int)(wd[p] << 24)) >> 28;
    uint32_t f0 = __builtin_bit_cast(uint32_t, (float)v0);  // exact in bf16
    uint32_t f1 = __builtin_bit_cast(uint32_t, (float)v1);
    op[p] = __builtin_amdgcn_perm(f1, f0, 0x07060302u);
  }
  *reinterpret_cast<uint4*>(Wb + i * 8) = o;
}

// ---------------- 256x256 bf16 GEMM: 1-barrier/K-tile overlapped pipeline ----------------
// 512 threads = 8 waves (2 M x 4 N). Per-wave output 128x64 -> acc[8][4].
// LDS: A ring 4 x 16KB + B ring 4 x 16KB = 128 KB (1 block/CU).
// Per K-tile: issue 12 ds_read_b128 + 4 global_load_lds, then 2x16 MFMA clusters
// with COMPILER-managed counted lgkmcnt (no manual lgkmcnt(0), no sched_barrier).
// Single boundary per K-tile: asm{vmcnt(N); s_barrier} with "memory" clobber —
// pins ds_reads on both sides (a read sinking past the boundary would race the
// re-stage of buffer kt&3 at iteration kt+1).
// Ledger: 4 loads/tile, 3 tiles in flight -> boundary vmcnt(8) publishes tile kt+1.

static constexpr int BM = 256, BN = 256, BK = 32;
static constexpr int NT = KTOT / BK;  // 128 K-tiles

__global__ __launch_bounds__(512, 2) void gemm_bf16_256_kernel(
    const ushort* __restrict__ Xb,   // [MTOT][KTOT] bf16
    const ushort* __restrict__ Wb,   // [NTOT][KTOT] bf16 (B^T layout)
    const float* __restrict__ scale,
    const float* __restrict__ bias,
    float* __restrict__ Y)
{
  __shared__ ushort As[4 * 8192];   // 4 bufs x (256 rows x 32 cols)
  __shared__ ushort Bs[4 * 8192];

  const int t    = threadIdx.x;
  const int lane = t & 63;
  const int wv   = t >> 6;       // 0..7
  const int wr   = wv >> 2;      // 0..1  (M half)
  const int wcn  = wv & 3;       // 0..3  (N quarter)

  // XCD mapping: xcd owns 4 M-tile rows; s>>2 sweeps N so all XCDs share W panels via L3
  const int wg  = blockIdx.x;          // 2048 blocks = 32 bm x 64 bn
  const int xcd = wg & 7;
  const int s   = wg >> 3;             // 0..255
  const int bm0 = (xcd * 4 + (s & 3)) * BM;
  const int bn0 = (s >> 2) * BN;

  // ---- staging addressing (inverse-swizzled global source, linear LDS dest)
  const int srow = wv * 16 + (lane >> 2);
  const int scol = 8 * ((lane & 3) ^ ((lane >> 2) & 3) ^ (lane >> 4));
  const ushort* agA = Xb + (size_t)(bm0 + srow) * KTOT + scol;
  const ushort* agB = Wb + (size_t)(bn0 + srow) * KTOT + scol;
  const size_t rowstep = (size_t)128 * KTOT;   // j=1 offset in source
  ushort* aldsw = As + wv * 512;               // + buf*8192 + j*4096 (lane*16B added by HW)
  ushort* bldsw = Bs + wv * 512;

  // ---- ds_read fragment addressing (swizzled column)
  const int rcol = 8 * ((lane >> 4) ^ (lane & 3) ^ ((lane >> 2) & 3));
  const ushort* Abase = As + (wr * 128 + (lane & 15)) * 32 + rcol;  // + buf*8192 + m*512
  const ushort* Bbase = Bs + (wcn * 64 + (lane & 15)) * 32 + rcol;  // + buf*8192 + n*512

  floatx4 acc[8][4];
  #pragma unroll
  for (int m = 0; m < 8; ++m)
    #pragma unroll
    for (int n = 0; n < 4; ++n)
      acc[m][n] = (floatx4){0.f, 0.f, 0.f, 0.f};

  // ---- prologue: stage tiles 0,1,2 (12 loads), publish tile 0 (keep 8 in flight)
  #pragma unroll
  for (int pt = 0; pt < 3; ++pt) {
    const size_t kof = (size_t)pt * BK;
    GLOAD_LDS16(agA + kof,           aldsw + pt * 8192);
    GLOAD_LDS16(agA + kof + rowstep, aldsw + pt * 8192 + 4096);
    GLOAD_LDS16(agB + kof,           bldsw + pt * 8192);
    GLOAD_LDS16(agB + kof + rowstep, bldsw + pt * 8192 + 4096);
  }
  asm volatile("s_waitcnt vmcnt(8)\ns_barrier" ::: "memory");

  for (int kt = 0; kt < NT; ++kt) {
    const int c  = kt & 3;
    const ushort* Ab = Abase + c * 8192;
    const ushort* Bb = Bbase + c * 8192;
    const int st = kt + 3;
    const bool do_stage = (st < NT);
    const int sb = st & 3;
    const size_t kof = (size_t)st * BK;

    // ---- issue ALL fragment reads for this K-tile (12 x ds_read_b128)
    short8 bf[4], af0[4], af1[4];
    #pragma unroll
    for (int n = 0; n < 4; ++n)
      bf[n] = *reinterpret_cast<const short8*>(Bb + n * 512);
    #pragma unroll
    for (int m = 0; m < 4; ++m)
      af0[m] = *reinterpret_cast<const short8*>(Ab + m * 512);
    #pragma unroll
    for (int m = 0; m < 4; ++m)
      af1[m] = *reinterpret_cast<const short8*>(Ab + (m + 4) * 512);

    // ---- issue stage of tile kt+3 (async, lands by boundary of kt+2)
    if (do_stage) {
      GLOAD_LDS16(agA + kof,           aldsw + sb * 8192);
      GLOAD_LDS16(agA + kof + rowstep, aldsw + sb * 8192 + 4096);
      GLOAD_LDS16(agB + kof,           bldsw + sb * 8192);
      GLOAD_LDS16(agB + kof + rowstep, bldsw + sb * 8192 + 4096);
    }

    // ---- MFMA clusters; compiler inserts counted lgkmcnt before each first use
    __builtin_amdgcn_s_setprio(1);
    #pragma unroll
    for (int m = 0; m < 4; ++m)
      #pragma unroll
      for (int n = 0; n < 4; ++n)
        acc[m][n] = __builtin_amdgcn_mfma_f32_16x16x32_bf16(af0[m], bf[n], acc[m][n], 0, 0, 0);
    #pragma unroll
    for (int m = 0; m < 4; ++m)
      #pragma unroll
      for (int n = 0; n < 4; ++n)
        acc[m + 4][n] = __builtin_amdgcn_mfma_f32_16x16x32_bf16(af1[m], bf[n], acc[m + 4][n], 0, 0, 0);
    __builtin_amdgcn_s_setprio(0);

    // ---- single K-tile boundary: counted vmcnt + barrier (one asm: memory-clobber
    //      fences ds_reads on both sides of the barrier)
    if (kt + 1 < NT) {
      if (kt + 4 <= NT)      { asm volatile("s_waitcnt vmcnt(8)\ns_barrier" ::: "memory"); }
      else if (kt + 3 <= NT) { asm volatile("s_waitcnt vmcnt(4)\ns_barrier" ::: "memory"); }
      else                   { asm volatile("s_waitcnt vmcnt(0)\ns_barrier" ::: "memory"); }
    }
  }

  // ---- epilogue: y = acc * scale[col] + bias[col]
  const int crow = (lane >> 4) * 4;  // C/D: row=(lane>>4)*4+reg, col=lane&15 (m89)
  const int ccol = lane & 15;
  #pragma unroll
  for (int n = 0; n < 4; ++n) {
    const int col  = bn0 + wcn * 64 + n * 16 + ccol;
    const float sc = scale[col];
    const float bz = bias[col];
    #pragma unroll
    for (int m = 0; m < 8; ++m) {
      const int row0 = bm0 + wr * 128 + m * 16 + crow;
      float* yp = Y + (size_t)row0 * NTOT + col;
      #pragma unroll
      for (int r = 0; r < 4; ++r)
        yp[(size_t)r * NTOT] = acc[m][n][r] * sc + bz;
    }
  }
}

// ---------------- fallback: fused kernel (round-2 passing version) ----------------

static constexpr int FBM = 128, FBN = 128, FBK = 64;
static constexpr int LDSS = 72;
static constexpr int FNSTEP = KTOT / FBK;

__global__ __launch_bounds__(256) void int4_linear_fused_kernel(
    const float* __restrict__ X,
    const uint32_t* __restrict__ Wp,
    const float* __restrict__ scale,
    const float* __restrict__ bias,
    float* __restrict__ Y)
{
  __shared__ ushort As[FBM * LDSS];
  __shared__ ushort Bs[FBN * LDSS];

  const int t    = threadIdx.x;
  const int lane = t & 63;
  const int wv   = t >> 6;
  const int wr   = wv >> 1;
  const int wc   = wv & 1;
  const int bm0 = blockIdx.y * FBM;
  const int bn0 = blockIdx.x * FBN;
  const int srow = t >> 1;
  const int sh   = t & 1;

  const float*    ag = X  + (size_t)(bm0 + srow) * KTOT + sh * 32;
  const uint32_t* bg = Wp + (size_t)(bn0 + srow) * (KTOT / 2) + sh * 16;

  float4 areg[8];
  uint4  breg[4];
  #pragma unroll
  for (int j = 0; j < 8; ++j) areg[j] = *reinterpret_cast<const float4*>(ag + j * 4);
  #pragma unroll
  for (int j = 0; j < 4; ++j) breg[j] = *reinterpret_cast<const uint4*>(bg + j * 4);

  floatx4 acc[4][4];
  #pragma unroll
  for (int m = 0; m < 4; ++m)
    #pragma unroll
    for (int n = 0; n < 4; ++n)
      acc[m][n] = (floatx4){0.f, 0.f, 0.f, 0.f};

  ushort* adst = &As[srow * LDSS + sh * 32];
  ushort* bdst = &Bs[srow * LDSS + sh * 32];

  for (int ks = 0; ks < FNSTEP; ++ks) {
    {
      uint32_t ab[16];
      #pragma unroll
      for (int j = 0; j < 8; ++j) {
        uint32_t u0 = __builtin_bit_cast(uint32_t, areg[j].x) + 0x8000u;
        uint32_t u1 = __builtin_bit_cast(uint32_t, areg[j].y) + 0x8000u;
        uint32_t u2 = __builtin_bit_cast(uint32_t, areg[j].z) + 0x8000u;
        uint32_t u3 = __builtin_bit_cast(uint32_t, areg[j].w) + 0x8000u;
        ab[2*j]   = __builtin_amdgcn_perm(u1, u0, 0x07060302u);
        ab[2*j+1] = __builtin_amdgcn_perm(u3, u2, 0x07060302u);
      }
      uint32_t bb[16];
      #pragma unroll
      for (int j = 0; j < 4; ++j) {
        const uint32_t wq[4] = {breg[j].x, breg[j].y, breg[j].z, breg[j].w};
        #pragma unroll
        for (int p = 0; p < 4; ++p) {
          const uint32_t w = wq[p];
          int v0 = ((int)(w << 28)) >> 28;
          int v1 = ((int)(w << 24)) >> 28;
          uint32_t f0 = __builtin_bit_cast(uint32_t, (float)v0);
          uint32_t f1 = __builtin_bit_cast(uint32_t, (float)v1);
          bb[j*4 + p] = __builtin_amdgcn_perm(f1, f0, 0x07060302u);
        }
      }
      #pragma unroll
      for (int j = 0; j < 4; ++j) {
        *reinterpret_cast<uint4*>(adst + j * 8) = *reinterpret_cast<const uint4*>(&ab[j*4]);
        *reinterpret_cast<uint4*>(bdst + j * 8) = *reinterpret_cast<const uint4*>(&bb[j*4]);
      }
    }
    __syncthreads();

    if (ks + 1 < FNSTEP) {
      const float*    ap = ag + (ks + 1) * FBK;
      const uint32_t* bp = bg + (ks + 1) * (FBK / 2);
      #pragma unroll
      for (int j = 0; j < 8; ++j) areg[j] = *reinterpret_cast<const float4*>(ap + j * 4);
      #pragma unroll
      for (int j = 0; j < 4; ++j) breg[j] = *reinterpret_cast<const uint4*>(bp + j * 4);
    }

    #pragma unroll
    for (int kk = 0; kk < 2; ++kk) {
      const int ko = kk * 32 + (lane >> 4) * 8;
      short8 af[4], bf[4];
      #pragma unroll
      for (int m = 0; m < 4; ++m)
        af[m] = *reinterpret_cast<const short8*>(&As[(wr*64 + m*16 + (lane & 15)) * LDSS + ko]);
      #pragma unroll
      for (int n = 0; n < 4; ++n)
        bf[n] = *reinterpret_cast<const short8*>(&Bs[(wc*64 + n*16 + (lane & 15)) * LDSS + ko]);
      #pragma unroll
      for (int m = 0; m < 4; ++m)
        #pragma unroll
        for (int n = 0; n < 4; ++n)
          acc[m][n] = __builtin_amdgcn_mfma_f32_16x16x32_bf16(af[m], bf[n], acc[m][n], 0, 0, 0);
    }
    __syncthreads();
  }

  const int crow = (lane >> 4) * 4;
  const int ccol = lane & 15;
  #pragma unroll
  for (int n = 0; n < 4; ++n) {
    const int col  = bn0 + wc * 64 + n * 16 + ccol;
    const float s  = scale[col];
    const float bz = bias[col];
    #pragma unroll
    for (int m = 0; m < 4; ++m) {
      const int row0 = bm0 + wr * 64 + m * 16 + crow;
      float* yp = Y + (size_t)row0 * NTOT + col;
      #pragma unroll
      for (int r = 0; r < 4; ++r)
        yp[(size_t)r * NTOT] = acc[m][n][r] * s + bz;
    }
  }
}

// ---------------- launch ----------------

extern "C" void kernel_launch(void* const* d_in, const int* in_sizes, int n_in,
                              void* d_out, int out_size, void* d_ws, size_t ws_size,
                              hipStream_t stream) {
  (void)in_sizes; (void)n_in; (void)out_size;
  const float*    X     = (const float*)d_in[0];
  const uint32_t* Wp    = (const uint32_t*)d_in[1];
  const float*    scale = (const float*)d_in[2];
  const float*    bias  = (const float*)d_in[3];
  float*          Y     = (float*)d_out;

  const size_t xb_bytes = (size_t)MTOT * KTOT * 2;          // 67 MB
  const size_t wb_bytes = (size_t)NTOT * KTOT * 2;          // 134 MB
  if (ws_size >= xb_bytes + wb_bytes) {
    ushort* Xb = (ushort*)d_ws;
    ushort* Wb = (ushort*)((char*)d_ws + xb_bytes);
    cvt_x_kernel<<<(MTOT * KTOT) / (8 * 256), 256, 0, stream>>>(X, Xb);
    cvt_w_kernel<<<(NTOT * KTOT / 2) / (4 * 256), 256, 0, stream>>>(Wp, Wb);
    gemm_bf16_256_kernel<<<(MTOT / BM) * (NTOT / BN), 512, 0, stream>>>(Xb, Wb, scale, bias, Y);
  } else {
    dim3 grid(NTOT / FBN, MTOT / FBM);
    int4_linear_fused_kernel<<<grid, 256, 0, stream>>>(X, Wp, scale, bias, Y);
  }
}

// Round 7
// 1105.417 us; speedup vs baseline: 2.6741x; 1.0692x over previous
//
#include <hip/hip_runtime.h>
#include <hip/hip_bf16.h>
#include <stdint.h>

typedef short short8 __attribute__((ext_vector_type(8)));
typedef float floatx4 __attribute__((ext_vector_type(4)));

static constexpr int KTOT = 4096;
static constexpr int NTOT = 16384;
static constexpr int MTOT = 8192;

#define GLOAD_LDS16(g, l)                                              \
  __builtin_amdgcn_global_load_lds(                                    \
      (const __attribute__((address_space(1))) void*)(g),              \
      (__attribute__((address_space(3))) void*)(l), 16, 0, 0)

__device__ __forceinline__ uint32_t pack2_bf16_rne(float lo, float hi) {
  uint32_t a = __builtin_bit_cast(uint32_t, lo);
  uint32_t b = __builtin_bit_cast(uint32_t, hi);
  a += 0x7FFFu + ((a >> 16) & 1u);
  b += 0x7FFFu + ((b >> 16) & 1u);
  return __builtin_amdgcn_perm(b, a, 0x07060302u);  // hi16(b)<<16 | hi16(a)
}

// ---------------- converters ----------------

__global__ __launch_bounds__(256) void cvt_x_kernel(
    const float* __restrict__ X, ushort* __restrict__ Xb) {
  const size_t i = (size_t)blockIdx.x * 256 + threadIdx.x;  // 8 floats/thread
  const float4 a = *reinterpret_cast<const float4*>(X + i * 8);
  const float4 b = *reinterpret_cast<const float4*>(X + i * 8 + 4);
  uint4 o;
  o.x = pack2_bf16_rne(a.x, a.y);
  o.y = pack2_bf16_rne(a.z, a.w);
  o.z = pack2_bf16_rne(b.x, b.y);
  o.w = pack2_bf16_rne(b.z, b.w);
  *reinterpret_cast<uint4*>(Xb + i * 8) = o;
}

__global__ __launch_bounds__(256) void cvt_w_kernel(
    const uint32_t* __restrict__ Wp, ushort* __restrict__ Wb) {
  const size_t i = (size_t)blockIdx.x * 256 + threadIdx.x;  // 4 words -> 8 bf16
  const uint4 w = *reinterpret_cast<const uint4*>(Wp + i * 4);
  const uint32_t wd[4] = {w.x, w.y, w.z, w.w};
  uint4 o;
  uint32_t* op = reinterpret_cast<uint32_t*>(&o);
  #pragma unroll
  for (int p = 0; p < 4; ++p) {
    // each int32 word holds one packed byte: low nibble = value 2q, high = 2q+1
    int v0 = ((int)(wd[p] << 28)) >> 28;
    int v1 = ((int)(wd[p] << 24)) >> 28;
    uint32_t f0 = __builtin_bit_cast(uint32_t, (float)v0);  // exact in bf16
    uint32_t f1 = __builtin_bit_cast(uint32_t, (float)v1);
    op[p] = __builtin_amdgcn_perm(f1, f0, 0x07060302u);
  }
  *reinterpret_cast<uint4*>(Wb + i * 8) = o;
}

// ------- 256x256 bf16 GEMM: fragment-double-buffered 1-barrier/K-tile pipeline -------
// 512 threads = 8 waves (2 M x 4 N). Per-wave output 128x64 -> acc[8][4].
// LDS: A ring 4 x 16KB + B ring 4 x 16KB = 128 KB (1 block/CU).
// Iter kt: issue 12 ds_read_b128 for tile kt+1's fragments; stage tile kt+3
// (global_load_lds); MFMA tile kt from regs read LAST iteration (lgkm wait ~free,
// LDS pipe overlaps matrix pipe within each wave). Boundary: vmcnt(4)+s_barrier
// publishes tile kt+2 for iter kt+1's reads (tile kt+3's 4 loads stay in flight).
// Frag sets named A/B, unroll-by-2 (rule #20: no runtime-indexed reg arrays).

static constexpr int BM = 256, BN = 256, BK = 32;
static constexpr int NT = KTOT / BK;  // 128 K-tiles

#define READ_FRAGS(AF0, AF1, BF, buf)                                   \
  {                                                                     \
    const ushort* Ab_ = Abase + (buf) * 8192;                           \
    const ushort* Bb_ = Bbase + (buf) * 8192;                           \
    _Pragma("unroll")                                                   \
    for (int n = 0; n < 4; ++n)                                         \
      BF[n] = *reinterpret_cast<const short8*>(Bb_ + n * 512);          \
    _Pragma("unroll")                                                   \
    for (int m = 0; m < 4; ++m)                                         \
      AF0[m] = *reinterpret_cast<const short8*>(Ab_ + m * 512);         \
    _Pragma("unroll")                                                   \
    for (int m = 0; m < 4; ++m)                                         \
      AF1[m] = *reinterpret_cast<const short8*>(Ab_ + (m + 4) * 512);   \
  }

#define STAGE(st_)                                                      \
  if ((st_) < NT) {                                                     \
    const int sb_ = (st_) & 3;                                          \
    const size_t kof_ = (size_t)(st_) * BK;                             \
    GLOAD_LDS16(agA + kof_,           aldsw + sb_ * 8192);              \
    GLOAD_LDS16(agA + kof_ + rowstep, aldsw + sb_ * 8192 + 4096);      \
    GLOAD_LDS16(agB + kof_,           bldsw + sb_ * 8192);              \
    GLOAD_LDS16(agB + kof_ + rowstep, bldsw + sb_ * 8192 + 4096);      \
  }

#define MFMA_CLUSTER(AF0, AF1, BF)                                      \
  __builtin_amdgcn_s_setprio(1);                                       \
  _Pragma("unroll")                                                     \
  for (int m = 0; m < 4; ++m)                                           \
    _Pragma("unroll")                                                   \
    for (int n = 0; n < 4; ++n)                                         \
      acc[m][n] = __builtin_amdgcn_mfma_f32_16x16x32_bf16(AF0[m], BF[n], acc[m][n], 0, 0, 0); \
  _Pragma("unroll")                                                     \
  for (int m = 0; m < 4; ++m)                                           \
    _Pragma("unroll")                                                   \
    for (int n = 0; n < 4; ++n)                                         \
      acc[m + 4][n] = __builtin_amdgcn_mfma_f32_16x16x32_bf16(AF1[m], BF[n], acc[m + 4][n], 0, 0, 0); \
  __builtin_amdgcn_s_setprio(0);

#define BOUNDARY(k_)                                                    \
  if ((k_) + 3 < NT) { asm volatile("s_waitcnt vmcnt(4)\ns_barrier" ::: "memory"); } \
  else               { asm volatile("s_waitcnt vmcnt(0)\ns_barrier" ::: "memory"); }

__global__ __launch_bounds__(512, 2) void gemm_bf16_256_kernel(
    const ushort* __restrict__ Xb,   // [MTOT][KTOT] bf16
    const ushort* __restrict__ Wb,   // [NTOT][KTOT] bf16 (B^T layout)
    const float* __restrict__ scale,
    const float* __restrict__ bias,
    float* __restrict__ Y)
{
  __shared__ ushort As[4 * 8192];   // 4 bufs x (256 rows x 32 cols)
  __shared__ ushort Bs[4 * 8192];

  const int t    = threadIdx.x;
  const int lane = t & 63;
  const int wv   = t >> 6;       // 0..7
  const int wr   = wv >> 2;      // 0..1  (M half)
  const int wcn  = wv & 3;       // 0..3  (N quarter)

  // XCD mapping: xcd owns 4 M-tile rows; s>>2 sweeps N so all XCDs share W panels via L3
  const int wg  = blockIdx.x;          // 2048 blocks = 32 bm x 64 bn
  const int xcd = wg & 7;
  const int s   = wg >> 3;             // 0..255
  const int bm0 = (xcd * 4 + (s & 3)) * BM;
  const int bn0 = (s >> 2) * BN;

  // ---- staging addressing (inverse-swizzled global source, linear LDS dest)
  const int srow = wv * 16 + (lane >> 2);
  const int scol = 8 * ((lane & 3) ^ ((lane >> 2) & 3) ^ (lane >> 4));
  const ushort* agA = Xb + (size_t)(bm0 + srow) * KTOT + scol;
  const ushort* agB = Wb + (size_t)(bn0 + srow) * KTOT + scol;
  const size_t rowstep = (size_t)128 * KTOT;   // j=1 offset in source
  ushort* aldsw = As + wv * 512;               // + buf*8192 + j*4096 (lane*16B added by HW)
  ushort* bldsw = Bs + wv * 512;

  // ---- ds_read fragment addressing (swizzled column)
  const int rcol = 8 * ((lane >> 4) ^ (lane & 3) ^ ((lane >> 2) & 3));
  const ushort* Abase = As + (wr * 128 + (lane & 15)) * 32 + rcol;  // + buf*8192 + m*512
  const ushort* Bbase = Bs + (wcn * 64 + (lane & 15)) * 32 + rcol;  // + buf*8192 + n*512

  floatx4 acc[8][4];
  #pragma unroll
  for (int m = 0; m < 8; ++m)
    #pragma unroll
    for (int n = 0; n < 4; ++n)
      acc[m][n] = (floatx4){0.f, 0.f, 0.f, 0.f};

  // ---- prologue: stage tiles 0,1,2 (12 loads); publish tiles 0 AND 1 (vmcnt(4))
  #pragma unroll
  for (int pt = 0; pt < 3; ++pt) {
    const size_t kof = (size_t)pt * BK;
    GLOAD_LDS16(agA + kof,           aldsw + pt * 8192);
    GLOAD_LDS16(agA + kof + rowstep, aldsw + pt * 8192 + 4096);
    GLOAD_LDS16(agB + kof,           bldsw + pt * 8192);
    GLOAD_LDS16(agB + kof + rowstep, bldsw + pt * 8192 + 4096);
  }
  asm volatile("s_waitcnt vmcnt(4)\ns_barrier" ::: "memory");

  // fragment sets: A = current tile, B = next tile (swap roles each sub-iter)
  short8 a0A[4], a1A[4], bA[4];
  short8 a0B[4], a1B[4], bB[4];
  READ_FRAGS(a0A, a1A, bA, 0);   // tile 0 fragments

  for (int kt = 0; kt < NT; kt += 2) {
    // ---- even sub-iter: read tile kt+1 frags; stage kt+3; MFMA tile kt
    READ_FRAGS(a0B, a1B, bB, (kt + 1) & 3);
    STAGE(kt + 3);
    MFMA_CLUSTER(a0A, a1A, bA);
    BOUNDARY(kt);

    // ---- odd sub-iter: read tile kt+2 frags; stage kt+4; MFMA tile kt+1
    if (kt + 2 < NT) { READ_FRAGS(a0A, a1A, bA, (kt + 2) & 3); }
    STAGE(kt + 4);
    MFMA_CLUSTER(a0B, a1B, bB);
    if (kt + 2 < NT) { BOUNDARY(kt + 1); }
  }

  // ---- epilogue: y = acc * scale[col] + bias[col]
  const int crow = (lane >> 4) * 4;  // C/D: row=(lane>>4)*4+reg, col=lane&15 (m89)
  const int ccol = lane & 15;
  #pragma unroll
  for (int n = 0; n < 4; ++n) {
    const int col  = bn0 + wcn * 64 + n * 16 + ccol;
    const float sc = scale[col];
    const float bz = bias[col];
    #pragma unroll
    for (int m = 0; m < 8; ++m) {
      const int row0 = bm0 + wr * 128 + m * 16 + crow;
      float* yp = Y + (size_t)row0 * NTOT + col;
      #pragma unroll
      for (int r = 0; r < 4; ++r)
        yp[(size_t)r * NTOT] = acc[m][n][r] * sc + bz;
    }
  }
}

// ---------------- fallback: fused kernel (round-2 passing version) ----------------

static constexpr int FBM = 128, FBN = 128, FBK = 64;
static constexpr int LDSS = 72;
static constexpr int FNSTEP = KTOT / FBK;

__global__ __launch_bounds__(256) void int4_linear_fused_kernel(
    const float* __restrict__ X,
    const uint32_t* __restrict__ Wp,
    const float* __restrict__ scale,
    const float* __restrict__ bias,
    float* __restrict__ Y)
{
  __shared__ ushort As[FBM * LDSS];
  __shared__ ushort Bs[FBN * LDSS];

  const int t    = threadIdx.x;
  const int lane = t & 63;
  const int wv   = t >> 6;
  const int wr   = wv >> 1;
  const int wc   = wv & 1;
  const int bm0 = blockIdx.y * FBM;
  const int bn0 = blockIdx.x * FBN;
  const int srow = t >> 1;
  const int sh   = t & 1;

  const float*    ag = X  + (size_t)(bm0 + srow) * KTOT + sh * 32;
  const uint32_t* bg = Wp + (size_t)(bn0 + srow) * (KTOT / 2) + sh * 16;

  float4 areg[8];
  uint4  breg[4];
  #pragma unroll
  for (int j = 0; j < 8; ++j) areg[j] = *reinterpret_cast<const float4*>(ag + j * 4);
  #pragma unroll
  for (int j = 0; j < 4; ++j) breg[j] = *reinterpret_cast<const uint4*>(bg + j * 4);

  floatx4 acc[4][4];
  #pragma unroll
  for (int m = 0; m < 4; ++m)
    #pragma unroll
    for (int n = 0; n < 4; ++n)
      acc[m][n] = (floatx4){0.f, 0.f, 0.f, 0.f};

  ushort* adst = &As[srow * LDSS + sh * 32];
  ushort* bdst = &Bs[srow * LDSS + sh * 32];

  for (int ks = 0; ks < FNSTEP; ++ks) {
    {
      uint32_t ab[16];
      #pragma unroll
      for (int j = 0; j < 8; ++j) {
        uint32_t u0 = __builtin_bit_cast(uint32_t, areg[j].x) + 0x8000u;
        uint32_t u1 = __builtin_bit_cast(uint32_t, areg[j].y) + 0x8000u;
        uint32_t u2 = __builtin_bit_cast(uint32_t, areg[j].z) + 0x8000u;
        uint32_t u3 = __builtin_bit_cast(uint32_t, areg[j].w) + 0x8000u;
        ab[2*j]   = __builtin_amdgcn_perm(u1, u0, 0x07060302u);
        ab[2*j+1] = __builtin_amdgcn_perm(u3, u2, 0x07060302u);
      }
      uint32_t bb[16];
      #pragma unroll
      for (int j = 0; j < 4; ++j) {
        const uint32_t wq[4] = {breg[j].x, breg[j].y, breg[j].z, breg[j].w};
        #pragma unroll
        for (int p = 0; p < 4; ++p) {
          const uint32_t w = wq[p];
          int v0 = ((int)(w << 28)) >> 28;
          int v1 = ((int)(w << 24)) >> 28;
          uint32_t f0 = __builtin_bit_cast(uint32_t, (float)v0);
          uint32_t f1 = __builtin_bit_cast(uint32_t, (float)v1);
          bb[j*4 + p] = __builtin_amdgcn_perm(f1, f0, 0x07060302u);
        }
      }
      #pragma unroll
      for (int j = 0; j < 4; ++j) {
        *reinterpret_cast<uint4*>(adst + j * 8) = *reinterpret_cast<const uint4*>(&ab[j*4]);
        *reinterpret_cast<uint4*>(bdst + j * 8) = *reinterpret_cast<const uint4*>(&bb[j*4]);
      }
    }
    __syncthreads();

    if (ks + 1 < FNSTEP) {
      const float*    ap = ag + (ks + 1) * FBK;
      const uint32_t* bp = bg + (ks + 1) * (FBK / 2);
      #pragma unroll
      for (int j = 0; j < 8; ++j) areg[j] = *reinterpret_cast<const float4*>(ap + j * 4);
      #pragma unroll
      for (int j = 0; j < 4; ++j) breg[j] = *reinterpret_cast<const uint4*>(bp + j * 4);
    }

    #pragma unroll
    for (int kk = 0; kk < 2; ++kk) {
      const int ko = kk * 32 + (lane >> 4) * 8;
      short8 af[4], bf[4];
      #pragma unroll
      for (int m = 0; m < 4; ++m)
        af[m] = *reinterpret_cast<const short8*>(&As[(wr*64 + m*16 + (lane & 15)) * LDSS + ko]);
      #pragma unroll
      for (int n = 0; n < 4; ++n)
        bf[n] = *reinterpret_cast<const short8*>(&Bs[(wc*64 + n*16 + (lane & 15)) * LDSS + ko]);
      #pragma unroll
      for (int m = 0; m < 4; ++m)
        #pragma unroll
        for (int n = 0; n < 4; ++n)
          acc[m][n] = __builtin_amdgcn_mfma_f32_16x16x32_bf16(af[m], bf[n], acc[m][n], 0, 0, 0);
    }
    __syncthreads();
  }

  const int crow = (lane >> 4) * 4;
  const int ccol = lane & 15;
  #pragma unroll
  for (int n = 0; n < 4; ++n) {
    const int col  = bn0 + wc * 64 + n * 16 + ccol;
    const float s  = scale[col];
    const float bz = bias[col];
    #pragma unroll
    for (int m = 0; m < 4; ++m) {
      const int row0 = bm0 + wr * 64 + m * 16 + crow;
      float* yp = Y + (size_t)row0 * NTOT + col;
      #pragma unroll
      for (int r = 0; r < 4; ++r)
        yp[(size_t)r * NTOT] = acc[m][n][r] * s + bz;
    }
  }
}

// ---------------- launch ----------------

extern "C" void kernel_launch(void* const* d_in, const int* in_sizes, int n_in,
                              void* d_out, int out_size, void* d_ws, size_t ws_size,
                              hipStream_t stream) {
  (void)in_sizes; (void)n_in; (void)out_size;
  const float*    X     = (const float*)d_in[0];
  const uint32_t* Wp    = (const uint32_t*)d_in[1];
  const float*    scale = (const float*)d_in[2];
  const float*    bias  = (const float*)d_in[3];
  float*          Y     = (float*)d_out;

  const size_t xb_bytes = (size_t)MTOT * KTOT * 2;          // 67 MB
  const size_t wb_bytes = (size_t)NTOT * KTOT * 2;          // 134 MB
  if (ws_size >= xb_bytes + wb_bytes) {
    ushort* Xb = (ushort*)d_ws;
    ushort* Wb = (ushort*)((char*)d_ws + xb_bytes);
    cvt_x_kernel<<<(MTOT * KTOT) / (8 * 256), 256, 0, stream>>>(X, Xb);
    cvt_w_kernel<<<(NTOT * KTOT / 2) / (4 * 256), 256, 0, stream>>>(Wp, Wb);
    gemm_bf16_256_kernel<<<(MTOT / BM) * (NTOT / BN), 512, 0, stream>>>(Xb, Wb, scale, bias, Y);
  } else {
    dim3 grid(NTOT / FBN, MTOT / FBM);
    int4_linear_fused_kernel<<<grid, 256, 0, stream>>>(X, Wp, scale, bias, Y);
  }
}